// Round 3
// baseline (7347.027 us; speedup 1.0000x reference)
//
#include <hip/hip_runtime.h>
#include <math.h>

#define BATCH 256
#define TT    784
#define HH    512
#define NCLS  10

#define NB 32          // batch groups
#define NJ 8           // j groups (blocks per group)
#define MB 8           // batch rows per group   (BATCH/NB)
#define HJ 64          // output cols per block  (HH/NJ)
#define NT 512         // threads per block (8 waves)

// thread map inside a block: j = tid&15 (16 lanes), kg = tid>>4 (32 k-chunks of 16)
// each thread owns 4 columns {j, j+16, j+32, j+48} over k-range [kg*16, kg*16+16)

// d_ws layout:
//   [0, 4096)                 : barrier counters, NB counters at stride 32 ints
//   [4096, 4096 + 2*B*H*4)    : double-buffered h state

__global__ __launch_bounds__(256) void rnn_init_kernel(float* hbuf0, int* cnt) {
    int i = blockIdx.x * blockDim.x + threadIdx.x;
    if (i < BATCH * HH) hbuf0[i] = 0.0f;   // h_0 = 0 (buffer 0)
    if (i < NB * 32)    cnt[i]   = 0;      // barrier counters
}

__global__ __launch_bounds__(NT, 2) void rnn_main_kernel(
    const float* __restrict__ inputs, const int* __restrict__ order,
    const float* __restrict__ W_ih, const float* __restrict__ b_ih,
    const float* __restrict__ W_hh, const float* __restrict__ b_hh,
    float* __restrict__ hbuf, int* cnt)
{
    __shared__ float hp[MB * HH];            // 16 KB: h tile
    __shared__ float pbuf[32 * MB * HJ];     // 64 KB: partials [kg][b][slot], slot = j*4 + colgrp
    __shared__ float xall[TT * MB];          // 25 KB: pre-gathered inputs[b][order[t]]
    __shared__ float wih_s[HJ];
    __shared__ float bias_s[HJ];

    const int tid   = threadIdx.x;
    const int blk   = blockIdx.x;
    const int bb    = blk & (NB - 1);   // group members blk=bb+32g -> same XCD under %8 round-robin
    const int jjg   = blk >> 5;         // j group 0..7
    const int jbase = jjg * HJ;
    const int bbase = bb * MB;
    const int j   = tid & 15;           // lane-within-16: base column
    const int kg  = tid >> 4;           // k-chunk 0..31 (16 k each)
    const int kg4 = kg * 4;             // float4 offset within a 512-float h row

    // ---- W_hh slice in NAMED registers: 4 cols x 16 k = 16 float4
    const float4* wp0 = (const float4*)(W_hh + (size_t)(jbase + j +  0) * HH + kg * 16);
    const float4* wp1 = (const float4*)(W_hh + (size_t)(jbase + j + 16) * HH + kg * 16);
    const float4* wp2 = (const float4*)(W_hh + (size_t)(jbase + j + 32) * HH + kg * 16);
    const float4* wp3 = (const float4*)(W_hh + (size_t)(jbase + j + 48) * HH + kg * 16);
    const float4 wa0 = wp0[0], wa1 = wp0[1], wa2 = wp0[2], wa3 = wp0[3];
    const float4 wb0 = wp1[0], wb1 = wp1[1], wb2 = wp1[2], wb3 = wp1[3];
    const float4 wc0 = wp2[0], wc1 = wp2[1], wc2 = wp2[2], wc3 = wp2[3];
    const float4 wd0 = wp3[0], wd1 = wp3[1], wd2 = wp3[2], wd3 = wp3[3];

    if (tid < HJ) {
        wih_s[tid]  = W_ih[jbase + tid];
        bias_s[tid] = b_ih[jbase + tid] + b_hh[jbase + tid];
    }
    // ---- pre-gather all x_t: xall[t*MB + b] = inputs[bbase+b][order[t]]
    for (int idx = tid; idx < TT * MB; idx += NT) {
        const int t = idx >> 3;          // MB == 8
        const int b = idx & (MB - 1);
        xall[idx] = inputs[(size_t)(bbase + b) * TT + order[t]];
    }

    int* mycnt = cnt + bb * 32;
    const float4* hp4 = (const float4*)hp;
    float4* P4 = (float4*)pbuf;          // P4[(kg*8+b)*16 + j]

    for (int t = 0; t < TT; ++t) {
        const int p = t & 1;
        if (t > 0 && tid == 0) {
            while (__hip_atomic_load(mycnt, __ATOMIC_ACQUIRE, __HIP_MEMORY_SCOPE_AGENT) < NJ * t) { }
        }
        __syncthreads();

        // ---- load h tile (MB x HH = 16 KB) from hbuf[p]
        {
            const float4* src = (const float4*)(hbuf + (size_t)p * BATCH * HH + (size_t)bbase * HH);
            float4* dst = (float4*)hp;
            dst[tid]      = src[tid];
            dst[tid + NT] = src[tid + NT];
        }
        __syncthreads();

        // ---- partial dot products: each h float4 feeds 4 columns
        float a00=0.f,a01=0.f,a02=0.f,a03=0.f,a04=0.f,a05=0.f,a06=0.f,a07=0.f;
        float a10=0.f,a11=0.f,a12=0.f,a13=0.f,a14=0.f,a15=0.f,a16=0.f,a17=0.f;
        float a20=0.f,a21=0.f,a22=0.f,a23=0.f,a24=0.f,a25=0.f,a26=0.f,a27=0.f;
        float a30=0.f,a31=0.f,a32=0.f,a33=0.f,a34=0.f,a35=0.f,a36=0.f,a37=0.f;

#define FMA4(ACC, WV, HV) \
        ACC = fmaf(WV.x, HV.x, ACC); ACC = fmaf(WV.y, HV.y, ACC); \
        ACC = fmaf(WV.z, HV.z, ACC); ACC = fmaf(WV.w, HV.w, ACC);
#define ROW(B) { \
        const float4* hr = hp4 + (B)*128 + kg4; \
        const float4 h0 = hr[0], h1 = hr[1], h2 = hr[2], h3 = hr[3]; \
        FMA4(a0##B, wa0, h0) FMA4(a0##B, wa1, h1) FMA4(a0##B, wa2, h2) FMA4(a0##B, wa3, h3) \
        FMA4(a1##B, wb0, h0) FMA4(a1##B, wb1, h1) FMA4(a1##B, wb2, h2) FMA4(a1##B, wb3, h3) \
        FMA4(a2##B, wc0, h0) FMA4(a2##B, wc1, h1) FMA4(a2##B, wc2, h2) FMA4(a2##B, wc3, h3) \
        FMA4(a3##B, wd0, h0) FMA4(a3##B, wd1, h1) FMA4(a3##B, wd2, h2) FMA4(a3##B, wd3, h3) }

        ROW(0) ROW(1) ROW(2) ROW(3) ROW(4) ROW(5) ROW(6) ROW(7)
#undef ROW
#undef FMA4

        __syncthreads();                 // h reads done
        // ---- partial writes: float4 over the 4 col-groups, slot = j*4+i
        {
            float4* dst = P4 + (size_t)kg * 128 + j;   // (kg*8+b)*16 + j
            dst[0*16] = make_float4(a00, a10, a20, a30);
            dst[1*16] = make_float4(a01, a11, a21, a31);
            dst[2*16] = make_float4(a02, a12, a22, a32);
            dst[3*16] = make_float4(a03, a13, a23, a33);
            dst[4*16] = make_float4(a04, a14, a24, a34);
            dst[5*16] = make_float4(a05, a15, a25, a35);
            dst[6*16] = make_float4(a06, a16, a26, a36);
            dst[7*16] = make_float4(a07, a17, a27, a37);
        }
        __syncthreads();

        // ---- reduce 32 k-chunks (2 waves), add input/bias, tanh, publish h_{t+1}
        if (tid < 128) {
            const int rb = tid >> 4;     // batch row 0..7
            const int rj = tid & 15;     // base column lane
            float4 s = P4[rb * 16 + rj];
            #pragma unroll
            for (int g = 1; g < 32; ++g) {
                const float4 v = P4[(size_t)g * 128 + rb * 16 + rj];
                s.x += v.x; s.y += v.y; s.z += v.z; s.w += v.w;
            }
            const float xv = xall[t * MB + rb];
            const float h0 = tanhf(s.x + xv * wih_s[rj +  0] + bias_s[rj +  0]);
            const float h1 = tanhf(s.y + xv * wih_s[rj + 16] + bias_s[rj + 16]);
            const float h2 = tanhf(s.z + xv * wih_s[rj + 32] + bias_s[rj + 32]);
            const float h3 = tanhf(s.w + xv * wih_s[rj + 48] + bias_s[rj + 48]);
            float* drow = hbuf + (size_t)(p ^ 1) * BATCH * HH + (size_t)(bbase + rb) * HH + jbase;
            drow[rj +  0] = h0;
            drow[rj + 16] = h1;
            drow[rj + 32] = h2;
            drow[rj + 48] = h3;
        }
        __syncthreads();
        if (tid == 0) {
            // RELEASE (after barrier's vmcnt drain) orders the h stores before the counter bump
            __hip_atomic_fetch_add(mycnt, 1, __ATOMIC_RELEASE, __HIP_MEMORY_SCOPE_AGENT);
        }
    }
}

__global__ __launch_bounds__(256) void rnn_tail_kernel(
    const float* __restrict__ hfin,   // final h in hbuf buffer 0 (T even)
    const float* __restrict__ lin_W, const float* __restrict__ lin_b,
    const int* __restrict__ y, float* __restrict__ out)
{
    __shared__ float redf[256];
    __shared__ int   redi[256];
    const int b = threadIdx.x;
    const float* hrow = hfin + (size_t)b * HH;

    float logits[NCLS];
    #pragma unroll
    for (int c = 0; c < NCLS; ++c) {
        float s = lin_b[c];
        const float* wrow = lin_W + (size_t)c * HH;
        for (int k = 0; k < HH; k += 4) {
            float4 hv = *(const float4*)(hrow + k);
            float4 wv = *(const float4*)(wrow + k);
            s += hv.x * wv.x + hv.y * wv.y + hv.z * wv.z + hv.w * wv.w;
        }
        logits[c] = s;
    }
    int am = 0; float m = logits[0];
    #pragma unroll
    for (int c = 1; c < NCLS; ++c) if (logits[c] > m) { m = logits[c]; am = c; } // first-max = jnp.argmax
    float sum = 0.0f;
    #pragma unroll
    for (int c = 0; c < NCLS; ++c) sum += expf(logits[c] - m);
    const float lse = m + logf(sum);
    const int yy = y[b];
    redf[b] = lse - logits[yy];           // -logp[b, y[b]]
    redi[b] = (am == yy) ? 1 : 0;
    __syncthreads();
    for (int s2 = 128; s2 > 0; s2 >>= 1) {
        if (b < s2) { redf[b] += redf[b + s2]; redi[b] += redi[b + s2]; }
        __syncthreads();
    }
    if (b == 0) {
        out[0] = redf[0] / (float)BATCH;  // loss
        out[1] = (float)redi[0];          // correct count
    }
}

extern "C" void kernel_launch(void* const* d_in, const int* in_sizes, int n_in,
                              void* d_out, int out_size, void* d_ws, size_t ws_size,
                              hipStream_t stream) {
    const float* inputs = (const float*)d_in[0];
    const int*   y      = (const int*)  d_in[1];
    const int*   order  = (const int*)  d_in[2];
    const float* W_ih   = (const float*)d_in[3];
    const float* b_ih   = (const float*)d_in[4];
    const float* W_hh   = (const float*)d_in[5];
    const float* b_hh   = (const float*)d_in[6];
    const float* lin_W  = (const float*)d_in[7];
    const float* lin_b  = (const float*)d_in[8];
    float* out = (float*)d_out;

    int*   cnt  = (int*)d_ws;
    float* hbuf = (float*)((char*)d_ws + 4096);

    hipLaunchKernelGGL(rnn_init_kernel, dim3((BATCH * HH + 255) / 256), dim3(256), 0, stream,
                       hbuf, cnt);

    void* args[] = {(void*)&inputs, (void*)&order, (void*)&W_ih, (void*)&b_ih,
                    (void*)&W_hh, (void*)&b_hh, (void*)&hbuf, (void*)&cnt};
    hipError_t err = hipLaunchCooperativeKernel((void*)rnn_main_kernel,
                                                dim3(NB * NJ), dim3(NT), args, 0, stream);
    if (err != hipSuccess) {
        // fallback: 256 blocks x 1/CU are co-resident on an otherwise-empty device
        hipLaunchKernelGGL(rnn_main_kernel, dim3(NB * NJ), dim3(NT), 0, stream,
                           inputs, order, W_ih, b_ih, W_hh, b_hh, hbuf, cnt);
    }

    hipLaunchKernelGGL(rnn_tail_kernel, dim3(1), dim3(256), 0, stream,
                       (const float*)hbuf, lin_W, lin_b, y, out);
}

// Round 4
// 3714.400 us; speedup vs baseline: 1.9780x; 1.9780x over previous
//
#include <hip/hip_runtime.h>
#include <math.h>

#define BATCH 256
#define TT    784
#define HH    512
#define NCLS  10

#define NB 32          // batch groups
#define NJ 8           // j groups (blocks per group)
#define MB 8           // batch rows per group   (BATCH/NB)
#define HJ 64          // output cols per block  (HH/NJ)
#define NT 512         // threads per block (8 waves)

typedef unsigned long long ull;

// d_ws layout:
//   [0, 8192)      : flags int[NB][64]  (one 256 B row per group; slot g = producer jg)
//   [8192, ...)    : double-buffered h state (2 * B * H floats)
//
// ALL cross-block data (h, flags) moves via relaxed agent-scope atomics ->
// global_* with sc0 sc1 (bypass L1/L2, coherent at L3). No per-step
// buffer_inv / buffer_wbl2. Ordering: sc1 h-stores are acked at the
// coherence point when vmcnt drains (the __syncthreads before the flag
// store), so a consumer that observes flag>=t reads valid h from L3.

__global__ __launch_bounds__(256) void rnn_init_kernel(ull* hbuf0, int* flags) {
    int i = blockIdx.x * blockDim.x + threadIdx.x;
    if (i < BATCH * HH / 2)
        __hip_atomic_store(&hbuf0[i], 0ULL, __ATOMIC_RELAXED, __HIP_MEMORY_SCOPE_AGENT);
    if (i < NB * 64)
        __hip_atomic_store(&flags[i], 0, __ATOMIC_RELAXED, __HIP_MEMORY_SCOPE_AGENT);
}

__global__ __launch_bounds__(NT, 2) void rnn_main_kernel(
    const float* __restrict__ inputs, const int* __restrict__ order,
    const float* __restrict__ W_ih, const float* __restrict__ b_ih,
    const float* __restrict__ W_hh, const float* __restrict__ b_hh,
    float* __restrict__ hbuf, int* flags)
{
    __shared__ float hp[MB * HH];            // 16 KB: h tile
    __shared__ float pbuf[32 * MB * HJ];     // 64 KB: partials [kg][b][slot]
    __shared__ float xall[TT * MB];          // 25 KB: pre-gathered inputs[b][order[t]]
    __shared__ float wih_s[HJ];
    __shared__ float bias_s[HJ];

    const int tid   = threadIdx.x;
    const int blk   = blockIdx.x;
    const int bb    = blk & (NB - 1);   // group members blk=bb+32g -> same XCD under %8 round-robin
    const int jjg   = blk >> 5;         // j group 0..7
    const int jbase = jjg * HJ;
    const int bbase = bb * MB;
    const int j   = tid & 15;           // lane-within-16: base column
    const int kg  = tid >> 4;           // k-chunk 0..31 (16 k each)
    const int kg4 = kg * 4;             // float4 offset within a 512-float h row

    // ---- W_hh slice in NAMED registers: 4 cols x 16 k = 16 float4
    const float4* wp0 = (const float4*)(W_hh + (size_t)(jbase + j +  0) * HH + kg * 16);
    const float4* wp1 = (const float4*)(W_hh + (size_t)(jbase + j + 16) * HH + kg * 16);
    const float4* wp2 = (const float4*)(W_hh + (size_t)(jbase + j + 32) * HH + kg * 16);
    const float4* wp3 = (const float4*)(W_hh + (size_t)(jbase + j + 48) * HH + kg * 16);
    const float4 wa0 = wp0[0], wa1 = wp0[1], wa2 = wp0[2], wa3 = wp0[3];
    const float4 wb0 = wp1[0], wb1 = wp1[1], wb2 = wp1[2], wb3 = wp1[3];
    const float4 wc0 = wp2[0], wc1 = wp2[1], wc2 = wp2[2], wc3 = wp2[3];
    const float4 wd0 = wp3[0], wd1 = wp3[1], wd2 = wp3[2], wd3 = wp3[3];

    if (tid < HJ) {
        wih_s[tid]  = W_ih[jbase + tid];
        bias_s[tid] = b_ih[jbase + tid] + b_hh[jbase + tid];
    }
    // ---- pre-gather all x_t: xall[t*MB + b] = inputs[bbase+b][order[t]]
    for (int idx = tid; idx < TT * MB; idx += NT) {
        const int t = idx >> 3;          // MB == 8
        const int b = idx & (MB - 1);
        xall[idx] = inputs[(size_t)(bbase + b) * TT + order[t]];
    }

    int* gflags = flags + bb * 64;
    const float4* hp4 = (const float4*)hp;
    float4* P4 = (float4*)pbuf;          // P4[(kg*8+b)*16 + j]

    for (int t = 0; t < TT; ++t) {
        const int p = t & 1;

        // ---- wait for all NJ producers of this group to have published h_t
        if (t > 0) {
            if (tid < 64) {
                const int g = tid & 7;   // 8 flags, one cacheline; one wave-load per poll
                while (__hip_atomic_load(&gflags[g], __ATOMIC_RELAXED,
                                         __HIP_MEMORY_SCOPE_AGENT) < t) { }
            }
            __syncthreads();             // X: releases all waves; also fences LDS reuse
        }

        // ---- load h tile (MB x HH = 16 KB) from L3 via sc1 loads
        {
            const ull* src = (const ull*)(hbuf + (size_t)p * BATCH * HH + (size_t)bbase * HH);
            ull* hpu = (ull*)hp;
            #pragma unroll
            for (int i = 0; i < 4; ++i)
                hpu[i * NT + tid] = __hip_atomic_load(&src[i * NT + tid], __ATOMIC_RELAXED,
                                                      __HIP_MEMORY_SCOPE_AGENT);
        }
        __syncthreads();                 // A: hp ready

        // ---- partial dot products: each h float4 feeds 4 columns
        float a00=0.f,a01=0.f,a02=0.f,a03=0.f,a04=0.f,a05=0.f,a06=0.f,a07=0.f;
        float a10=0.f,a11=0.f,a12=0.f,a13=0.f,a14=0.f,a15=0.f,a16=0.f,a17=0.f;
        float a20=0.f,a21=0.f,a22=0.f,a23=0.f,a24=0.f,a25=0.f,a26=0.f,a27=0.f;
        float a30=0.f,a31=0.f,a32=0.f,a33=0.f,a34=0.f,a35=0.f,a36=0.f,a37=0.f;

#define FMA4(ACC, WV, HV) \
        ACC = fmaf(WV.x, HV.x, ACC); ACC = fmaf(WV.y, HV.y, ACC); \
        ACC = fmaf(WV.z, HV.z, ACC); ACC = fmaf(WV.w, HV.w, ACC);
#define ROW(B) { \
        const float4* hr = hp4 + (B)*128 + kg4; \
        const float4 h0 = hr[0], h1 = hr[1], h2 = hr[2], h3 = hr[3]; \
        FMA4(a0##B, wa0, h0) FMA4(a0##B, wa1, h1) FMA4(a0##B, wa2, h2) FMA4(a0##B, wa3, h3) \
        FMA4(a1##B, wb0, h0) FMA4(a1##B, wb1, h1) FMA4(a1##B, wb2, h2) FMA4(a1##B, wb3, h3) \
        FMA4(a2##B, wc0, h0) FMA4(a2##B, wc1, h1) FMA4(a2##B, wc2, h2) FMA4(a2##B, wc3, h3) \
        FMA4(a3##B, wd0, h0) FMA4(a3##B, wd1, h1) FMA4(a3##B, wd2, h2) FMA4(a3##B, wd3, h3) }

        ROW(0) ROW(1) ROW(2) ROW(3) ROW(4) ROW(5) ROW(6) ROW(7)
#undef ROW
#undef FMA4

        // ---- partial writes straight to pbuf (disjoint from hp: no barrier needed)
        {
            float4* dst = P4 + (size_t)kg * 128 + j;   // (kg*8+b)*16 + j
            dst[0*16] = make_float4(a00, a10, a20, a30);
            dst[1*16] = make_float4(a01, a11, a21, a31);
            dst[2*16] = make_float4(a02, a12, a22, a32);
            dst[3*16] = make_float4(a03, a13, a23, a33);
            dst[4*16] = make_float4(a04, a14, a24, a34);
            dst[5*16] = make_float4(a05, a15, a25, a35);
            dst[6*16] = make_float4(a06, a16, a26, a36);
            dst[7*16] = make_float4(a07, a17, a27, a37);
        }
        __syncthreads();                 // B: partials ready

        // ---- reduce 32 k-chunks (2 waves), add input/bias, tanh, publish via sc1 stores
        if (tid < 128) {
            const int rb = tid >> 4;     // batch row 0..7
            const int rj = tid & 15;     // base column lane
            float4 s = P4[rb * 16 + rj];
            #pragma unroll
            for (int g = 1; g < 32; ++g) {
                const float4 v = P4[(size_t)g * 128 + rb * 16 + rj];
                s.x += v.x; s.y += v.y; s.z += v.z; s.w += v.w;
            }
            const float xv = xall[t * MB + rb];
            const float h0 = tanhf(s.x + xv * wih_s[rj +  0] + bias_s[rj +  0]);
            const float h1 = tanhf(s.y + xv * wih_s[rj + 16] + bias_s[rj + 16]);
            const float h2 = tanhf(s.z + xv * wih_s[rj + 32] + bias_s[rj + 32]);
            const float h3 = tanhf(s.w + xv * wih_s[rj + 48] + bias_s[rj + 48]);
            float* drow = hbuf + (size_t)(p ^ 1) * BATCH * HH + (size_t)(bbase + rb) * HH + jbase;
            __hip_atomic_store(&drow[rj +  0], h0, __ATOMIC_RELAXED, __HIP_MEMORY_SCOPE_AGENT);
            __hip_atomic_store(&drow[rj + 16], h1, __ATOMIC_RELAXED, __HIP_MEMORY_SCOPE_AGENT);
            __hip_atomic_store(&drow[rj + 32], h2, __ATOMIC_RELAXED, __HIP_MEMORY_SCOPE_AGENT);
            __hip_atomic_store(&drow[rj + 48], h3, __ATOMIC_RELAXED, __HIP_MEMORY_SCOPE_AGENT);
        }
        __syncthreads();                 // C: every wave's sc1 h-stores acked (vmcnt drained)

        if (tid == 0)                    // publish: one sc1 dword, no RMW, no fence
            __hip_atomic_store(&gflags[jjg], t + 1, __ATOMIC_RELAXED, __HIP_MEMORY_SCOPE_AGENT);
    }
}

__global__ __launch_bounds__(256) void rnn_tail_kernel(
    const float* __restrict__ hfin,   // final h in hbuf buffer 0 (T even)
    const float* __restrict__ lin_W, const float* __restrict__ lin_b,
    const int* __restrict__ y, float* __restrict__ out)
{
    __shared__ float redf[256];
    __shared__ int   redi[256];
    const int b = threadIdx.x;
    const float* hrow = hfin + (size_t)b * HH;

    float logits[NCLS];
    #pragma unroll
    for (int c = 0; c < NCLS; ++c) {
        float s = lin_b[c];
        const float* wrow = lin_W + (size_t)c * HH;
        for (int k = 0; k < HH; k += 4) {
            float4 hv = *(const float4*)(hrow + k);
            float4 wv = *(const float4*)(wrow + k);
            s += hv.x * wv.x + hv.y * wv.y + hv.z * wv.z + hv.w * wv.w;
        }
        logits[c] = s;
    }
    int am = 0; float m = logits[0];
    #pragma unroll
    for (int c = 1; c < NCLS; ++c) if (logits[c] > m) { m = logits[c]; am = c; } // first-max = jnp.argmax
    float sum = 0.0f;
    #pragma unroll
    for (int c = 0; c < NCLS; ++c) sum += expf(logits[c] - m);
    const float lse = m + logf(sum);
    const int yy = y[b];
    redf[b] = lse - logits[yy];           // -logp[b, y[b]]
    redi[b] = (am == yy) ? 1 : 0;
    __syncthreads();
    for (int s2 = 128; s2 > 0; s2 >>= 1) {
        if (b < s2) { redf[b] += redf[b + s2]; redi[b] += redi[b + s2]; }
        __syncthreads();
    }
    if (b == 0) {
        out[0] = redf[0] / (float)BATCH;  // loss
        out[1] = (float)redi[0];          // correct count
    }
}

extern "C" void kernel_launch(void* const* d_in, const int* in_sizes, int n_in,
                              void* d_out, int out_size, void* d_ws, size_t ws_size,
                              hipStream_t stream) {
    const float* inputs = (const float*)d_in[0];
    const int*   y      = (const int*)  d_in[1];
    const int*   order  = (const int*)  d_in[2];
    const float* W_ih   = (const float*)d_in[3];
    const float* b_ih   = (const float*)d_in[4];
    const float* W_hh   = (const float*)d_in[5];
    const float* b_hh   = (const float*)d_in[6];
    const float* lin_W  = (const float*)d_in[7];
    const float* lin_b  = (const float*)d_in[8];
    float* out = (float*)d_out;

    int*   flags = (int*)d_ws;
    float* hbuf  = (float*)((char*)d_ws + 8192);

    hipLaunchKernelGGL(rnn_init_kernel, dim3(256), dim3(256), 0, stream,
                       (ull*)hbuf, flags);

    void* args[] = {(void*)&inputs, (void*)&order, (void*)&W_ih, (void*)&b_ih,
                    (void*)&W_hh, (void*)&b_hh, (void*)&hbuf, (void*)&flags};
    hipError_t err = hipLaunchCooperativeKernel((void*)rnn_main_kernel,
                                                dim3(NB * NJ), dim3(NT), args, 0, stream);
    if (err != hipSuccess) {
        // fallback: 256 blocks x 1/CU are co-resident on an otherwise-empty device
        hipLaunchKernelGGL(rnn_main_kernel, dim3(NB * NJ), dim3(NT), 0, stream,
                           inputs, order, W_ih, b_ih, W_hh, b_hh, hbuf, flags);
    }

    hipLaunchKernelGGL(rnn_tail_kernel, dim3(1), dim3(256), 0, stream,
                       (const float*)hbuf, lin_W, lin_b, y, out);
}